// Round 4
// baseline (760.520 us; speedup 1.0000x reference)
//
#include <hip/hip_runtime.h>
#include <hip/hip_bf16.h>
#include <math.h>

#define T_TOK 8192
#define NE 1024
#define N_EXP 8
#define DFFN 2048
#define TW 16384        // total width = 8*2048
#define P_TOT 16384     // T_TOK * 2

#define BM 256
#define BN 128
#define BKT 32

typedef __attribute__((ext_vector_type(8))) short bf16x8;
typedef __attribute__((ext_vector_type(4))) float f32x4;

#define GLOAD_LDS16(g, l) __builtin_amdgcn_global_load_lds( \
    (const __attribute__((address_space(1))) void*)(g), \
    (__attribute__((address_space(3))) void*)(l), 16, 0, 0)

static __device__ __forceinline__ unsigned short f2bf(float f) {
    __hip_bfloat16 b = __float2bfloat16(f);
    return *(unsigned short*)&b;
}

// ---------------------------------------------------------------------------
// Kernel A: router — logits, softmax, top-2, normalized weights, loss partials
// (f32 throughout: bf16 logits would flip near-tie top-k selections)
// ---------------------------------------------------------------------------
__global__ __launch_bounds__(256) void router_kernel(
    const float* __restrict__ x, const float* __restrict__ wr,
    int* __restrict__ sel_idx, float* __restrict__ sel_wt,
    float* __restrict__ z_part, float* __restrict__ p_part)
{
    __shared__ float wrs[N_EXP * NE];   // 32 KB
    __shared__ float red[256];
    int tid = threadIdx.x;
    for (int i = tid; i < N_EXP * NE; i += 256) wrs[i] = wr[i];
    __syncthreads();

    int t = blockIdx.x * 256 + tid;   // T_TOK == 32*256 exactly
    float lg[N_EXP];
#pragma unroll
    for (int e = 0; e < N_EXP; e++) lg[e] = 0.f;

    const float4* x4 = (const float4*)(x + (size_t)t * NE);
    for (int n4 = 0; n4 < NE / 4; n4++) {
        float4 xv = x4[n4];
#pragma unroll
        for (int e = 0; e < N_EXP; e++) {
            const float* w = &wrs[e * NE + n4 * 4];
            lg[e] += xv.x * w[0] + xv.y * w[1] + xv.z * w[2] + xv.w * w[3];
        }
    }

    float m = lg[0];
#pragma unroll
    for (int e = 1; e < N_EXP; e++) m = fmaxf(m, lg[e]);
    float p[N_EXP], s = 0.f;
#pragma unroll
    for (int e = 0; e < N_EXP; e++) { p[e] = expf(lg[e] - m); s += p[e]; }
    float inv = 1.f / s;
#pragma unroll
    for (int e = 0; e < N_EXP; e++) p[e] *= inv;
    float lse = m + logf(s);

    int e0 = 0;
#pragma unroll
    for (int e = 1; e < N_EXP; e++) if (p[e] > p[e0]) e0 = e;
    int e1 = (e0 == 0) ? 1 : 0;
#pragma unroll
    for (int e = 0; e < N_EXP; e++) if (e != e0 && p[e] > p[e1]) e1 = e;

    float wn = 1.f / (p[e0] + p[e1]);
    sel_idx[t * 2 + 0] = e0;
    sel_idx[t * 2 + 1] = e1;
    sel_wt[t * 2 + 0] = p[e0] * wn;
    sel_wt[t * 2 + 1] = p[e1] * wn;

    red[tid] = lse * lse;
    __syncthreads();
    for (int st = 128; st > 0; st >>= 1) {
        if (tid < st) red[tid] += red[tid + st];
        __syncthreads();
    }
    if (tid == 0) z_part[blockIdx.x] = red[0];
#pragma unroll
    for (int e = 0; e < N_EXP; e++) {
        __syncthreads();
        red[tid] = p[e];
        __syncthreads();
        for (int st = 128; st > 0; st >>= 1) {
            if (tid < st) red[tid] += red[tid + st];
            __syncthreads();
        }
        if (tid == 0) p_part[blockIdx.x * N_EXP + e] = red[0];
    }
}

// ---------------------------------------------------------------------------
// Kernel B: counts (by scan), offsets, cursors, tile table, work-queue reset,
// aux-loss outputs
// ---------------------------------------------------------------------------
__global__ __launch_bounds__(256) void finalize_router(
    const int* __restrict__ sel_idx,
    const float* __restrict__ z_part, const float* __restrict__ p_part,
    int* __restrict__ cnt, int* __restrict__ off, int* __restrict__ cursor,
    int* __restrict__ tile_tab, int* __restrict__ tile_n,
    int* __restrict__ wq,
    float* __restrict__ out)
{
    __shared__ int redc[256];
    __shared__ int cnts[N_EXP];
    int tid = threadIdx.x;
    int c[N_EXP];
#pragma unroll
    for (int e = 0; e < N_EXP; e++) c[e] = 0;
    for (int i = tid; i < P_TOT; i += 256) c[sel_idx[i]]++;
#pragma unroll
    for (int e = 0; e < N_EXP; e++) {
        redc[tid] = c[e];
        __syncthreads();
        for (int st = 128; st > 0; st >>= 1) {
            if (tid < st) redc[tid] += redc[tid + st];
            __syncthreads();
        }
        if (tid == 0) cnts[e] = redc[0];
        __syncthreads();
    }
    if (tid == 0) {
        int o = 0;
        int nt = 0;
        for (int e = 0; e < N_EXP; e++) {
            cnt[e] = cnts[e];
            off[e] = o;
            o += cnts[e];
            cursor[e] = 0;
            for (int rb = 0; rb < cnts[e]; rb += BM)
                tile_tab[nt++] = (e << 20) | rb;
        }
        off[N_EXP] = o;
        tile_n[0] = nt;
        wq[0] = 0;       // gemm1 work-queue ticket
        wq[1] = 0;       // gemm2 work-queue ticket
        float zs = 0.f;
        for (int b = 0; b < 32; b++) zs += z_part[b];
        float lb = 0.f;
        float* tail = out + (size_t)T_TOK * NE;
        for (int e = 0; e < N_EXP; e++) {
            float ps = 0.f;
            for (int b = 0; b < 32; b++) ps += p_part[b * N_EXP + e];
            float fi = (float)cnts[e] / (float)P_TOT;
            float pi = ps / (float)T_TOK;
            lb += fi * pi;
            tail[2 + e] = fi;
        }
        tail[0] = zs / (float)T_TOK;       // router_z_loss
        tail[1] = 8.f * lb;                // load_balance_loss
    }
}

// ---------------------------------------------------------------------------
// Kernel C: scatter (token,slot) pairs into per-expert lists
// ---------------------------------------------------------------------------
__global__ __launch_bounds__(256) void scatter_kernel(
    const int* __restrict__ sel_idx, const int* __restrict__ off,
    int* __restrict__ cursor, int* __restrict__ token_list)
{
    int i = blockIdx.x * 256 + threadIdx.x;
    if (i < P_TOT) {
        int e = sel_idx[i];
        int pos = atomicAdd(&cursor[e], 1);
        token_list[off[e] + pos] = i;   // token = i>>1, slot = i&1
    }
}

// ---------------------------------------------------------------------------
// Kernel P1: x f32 -> bf16 (same layout)
// ---------------------------------------------------------------------------
__global__ __launch_bounds__(256) void cvt_x_kernel(
    const float* __restrict__ x, unsigned short* __restrict__ xb)
{
    int i = blockIdx.x * 256 + threadIdx.x;     // one float4 per thread
    float4 v = ((const float4*)x)[i];
    ushort4 o;
    o.x = f2bf(v.x); o.y = f2bf(v.y); o.z = f2bf(v.z); o.w = f2bf(v.w);
    ((ushort4*)xb)[i] = o;
}

// ---------------------------------------------------------------------------
// Kernel P2: transpose + convert: src [R][C] f32 -> dst [C][R] bf16
// vectorized: float4 loads, ushort4 stores
// ---------------------------------------------------------------------------
__global__ __launch_bounds__(256) void transpose_bf16_kernel(
    const float* __restrict__ src, unsigned short* __restrict__ dst,
    int R, int C)
{
    __shared__ float tile[64][65];
    int rb = blockIdx.y * 64, cb = blockIdx.x * 64;
    int tid = threadIdx.x;
#pragma unroll
    for (int p = 0; p < 4; p++) {
        int idx = p * 256 + tid;
        int r = idx >> 4, c4 = (idx & 15) << 2;
        float4 v = *(const float4*)&src[(size_t)(rb + r) * C + cb + c4];
        tile[r][c4 + 0] = v.x; tile[r][c4 + 1] = v.y;
        tile[r][c4 + 2] = v.z; tile[r][c4 + 3] = v.w;
    }
    __syncthreads();
#pragma unroll
    for (int p = 0; p < 4; p++) {
        int idx = p * 256 + tid;
        int c = idx >> 4, r4 = (idx & 15) << 2;
        ushort4 o;
        o.x = f2bf(tile[r4 + 0][c]); o.y = f2bf(tile[r4 + 1][c]);
        o.z = f2bf(tile[r4 + 2][c]); o.w = f2bf(tile[r4 + 3][c]);
        *(ushort4*)&dst[(size_t)(cb + c) * R + rb + r4] = o;
    }
}

// ---------------------------------------------------------------------------
// Kernel D: grouped GEMM1, 256x128 tile, BK=32, 4 waves (2x2), dbuf LDS with
// XOR-swizzle (write-side: pre-swizzled global source; read-side: matching
// XOR on ds_read addr). Work-stealing over (row-tile, col-tile) items.
// h[p,:] = selw[p] * gelu(xb[tok(p),:] @ W1_e)
// ---------------------------------------------------------------------------
__global__ __launch_bounds__(256) void gemm1_mfma(
    const __hip_bfloat16* __restrict__ xb, const __hip_bfloat16* __restrict__ w1t,
    const int* __restrict__ token_list, const float* __restrict__ sel_wt,
    const int* __restrict__ cnt, const int* __restrict__ off,
    const int* __restrict__ tile_tab, const int* __restrict__ tile_n,
    int* __restrict__ wq,
    __hip_bfloat16* __restrict__ h)
{
    __shared__ __align__(16) __hip_bfloat16 As[2][BM * BKT];  // 32 KB
    __shared__ __align__(16) __hip_bfloat16 Bs[2][BN * BKT];  // 16 KB
    volatile int* wkslot = (volatile int*)&Bs[0][0];

    int tid = threadIdx.x;
    int w = tid >> 6, lane = tid & 63;
    int wm = w >> 1, wn = w & 1;
    int rr = lane & 15, kq = lane >> 4;
    int kqa = kq ^ ((rr >> 1) & 3);              // read-side swizzle
    int ksw = (lane & 3) ^ ((lane >> 3) & 3);    // write-side source swizzle
    int nwork = tile_n[0] * 16;                  // 16 col-tiles of 128

    for (;;) {
        if (tid == 0) *wkslot = atomicAdd(wq, 1);
        __syncthreads();
        int wk = *wkslot;
        __syncthreads();
        if (wk >= nwork) return;

        int tab = tile_tab[wk >> 4];
        int e = tab >> 20, rowbase = tab & 0xFFFFF;
        int off_e = off[e];
        int rows_e = cnt[e] - rowbase;
        int colbase = (wk & 15) * BN;

        const __hip_bfloat16* asrc[4];
        const __hip_bfloat16* bsrc[2];
#pragma unroll
        for (int q = 0; q < 4; q++) {
            int r = q * 64 + w * 16 + (lane >> 2);
            int ent = token_list[off_e + rowbase + ((r < rows_e) ? r : 0)];
            asrc[q] = xb + (size_t)(ent >> 1) * NE + ksw * 8;
        }
#pragma unroll
        for (int q = 0; q < 2; q++) {
            int cc = colbase + q * 64 + w * 16 + (lane >> 2);
            bsrc[q] = w1t + (size_t)(e * DFFN + cc) * NE + ksw * 8;
        }

        f32x4 acc[8][4] = {};

#pragma unroll
        for (int q = 0; q < 4; q++) GLOAD_LDS16(asrc[q], &As[0][q * 2048 + w * 512]);
#pragma unroll
        for (int q = 0; q < 2; q++) GLOAD_LDS16(bsrc[q], &Bs[0][q * 2048 + w * 512]);
        __syncthreads();

        for (int t = 0; t < NE / BKT; t++) {
            int cur = t & 1;
            if (t + 1 < NE / BKT) {
                int kb = (t + 1) * BKT;
#pragma unroll
                for (int q = 0; q < 4; q++)
                    GLOAD_LDS16(asrc[q] + kb, &As[cur ^ 1][q * 2048 + w * 512]);
#pragma unroll
                for (int q = 0; q < 2; q++)
                    GLOAD_LDS16(bsrc[q] + kb, &Bs[cur ^ 1][q * 2048 + w * 512]);
            }
            bf16x8 af[8], bfr[4];
#pragma unroll
            for (int m = 0; m < 8; m++)
                af[m] = *(const bf16x8*)&As[cur][(wm * 128 + m * 16 + rr) * BKT + kqa * 8];
#pragma unroll
            for (int n = 0; n < 4; n++)
                bfr[n] = *(const bf16x8*)&Bs[cur][(wn * 64 + n * 16 + rr) * BKT + kqa * 8];
#pragma unroll
            for (int m = 0; m < 8; m++)
#pragma unroll
                for (int n = 0; n < 4; n++)
                    acc[m][n] = __builtin_amdgcn_mfma_f32_16x16x32_bf16(
                        af[m], bfr[n], acc[m][n], 0, 0, 0);
            __syncthreads();
        }

        int colg = colbase + wn * 64;
#pragma unroll
        for (int m = 0; m < 8; m++) {
#pragma unroll
            for (int j = 0; j < 4; j++) {
                int r = wm * 128 + m * 16 + kq * 4 + j;
                if (r < rows_e) {
                    size_t p = (size_t)off_e + rowbase + r;
                    float wgt = sel_wt[token_list[p]];
#pragma unroll
                    for (int n = 0; n < 4; n++) {
                        float v = acc[m][n][j];
                        float g = 0.5f * v * (1.f + erff(v * 0.70710678118f));
                        h[p * DFFN + colg + n * 16 + rr] = __float2bfloat16(wgt * g);
                    }
                }
            }
        }
    }
}

// ---------------------------------------------------------------------------
// Kernel E: grouped GEMM2, same structure, split-K=2, atomic f32 out.
// out[tok(p),:] += h[p,:] @ W2_e
// ---------------------------------------------------------------------------
__global__ __launch_bounds__(256) void gemm2_mfma(
    const __hip_bfloat16* __restrict__ h, const __hip_bfloat16* __restrict__ w2t,
    const int* __restrict__ token_list,
    const int* __restrict__ cnt, const int* __restrict__ off,
    const int* __restrict__ tile_tab, const int* __restrict__ tile_n,
    int* __restrict__ wq,
    float* __restrict__ out)
{
    __shared__ __align__(16) __hip_bfloat16 As[2][BM * BKT];
    __shared__ __align__(16) __hip_bfloat16 Bs[2][BN * BKT];
    volatile int* wkslot = (volatile int*)&Bs[0][0];

    int tid = threadIdx.x;
    int w = tid >> 6, lane = tid & 63;
    int wm = w >> 1, wn = w & 1;
    int rr = lane & 15, kq = lane >> 4;
    int kqa = kq ^ ((rr >> 1) & 3);
    int ksw = (lane & 3) ^ ((lane >> 3) & 3);
    int nwork = tile_n[0] * 16;                 // 8 col-tiles x 2 splitK

    for (;;) {
        if (tid == 0) *wkslot = atomicAdd(wq, 1);
        __syncthreads();
        int wk = *wkslot;
        __syncthreads();
        if (wk >= nwork) return;

        int tab = tile_tab[wk >> 4];
        int e = tab >> 20, rowbase = tab & 0xFFFFF;
        int off_e = off[e];
        int rows_e = cnt[e] - rowbase;
        int colbase = ((wk >> 1) & 7) * BN;
        int k0 = (wk & 1) * 1024;               // split-K offset

        const __hip_bfloat16* asrc[4];
        const __hip_bfloat16* bsrc[2];
#pragma unroll
        for (int q = 0; q < 4; q++) {
            int r = q * 64 + w * 16 + (lane >> 2);
            int pr = off_e + rowbase + ((r < rows_e) ? r : 0);
            asrc[q] = h + (size_t)pr * DFFN + k0 + ksw * 8;
        }
#pragma unroll
        for (int q = 0; q < 2; q++) {
            int cc = colbase + q * 64 + w * 16 + (lane >> 2);
            bsrc[q] = w2t + (size_t)cc * TW + e * DFFN + k0 + ksw * 8;
        }

        f32x4 acc[8][4] = {};

#pragma unroll
        for (int q = 0; q < 4; q++) GLOAD_LDS16(asrc[q], &As[0][q * 2048 + w * 512]);
#pragma unroll
        for (int q = 0; q < 2; q++) GLOAD_LDS16(bsrc[q], &Bs[0][q * 2048 + w * 512]);
        __syncthreads();

        for (int t = 0; t < 1024 / BKT; t++) {
            int cur = t & 1;
            if (t + 1 < 1024 / BKT) {
                int kb = (t + 1) * BKT;
#pragma unroll
                for (int q = 0; q < 4; q++)
                    GLOAD_LDS16(asrc[q] + kb, &As[cur ^ 1][q * 2048 + w * 512]);
#pragma unroll
                for (int q = 0; q < 2; q++)
                    GLOAD_LDS16(bsrc[q] + kb, &Bs[cur ^ 1][q * 2048 + w * 512]);
            }
            bf16x8 af[8], bfr[4];
#pragma unroll
            for (int m = 0; m < 8; m++)
                af[m] = *(const bf16x8*)&As[cur][(wm * 128 + m * 16 + rr) * BKT + kqa * 8];
#pragma unroll
            for (int n = 0; n < 4; n++)
                bfr[n] = *(const bf16x8*)&Bs[cur][(wn * 64 + n * 16 + rr) * BKT + kqa * 8];
#pragma unroll
            for (int m = 0; m < 8; m++)
#pragma unroll
                for (int n = 0; n < 4; n++)
                    acc[m][n] = __builtin_amdgcn_mfma_f32_16x16x32_bf16(
                        af[m], bfr[n], acc[m][n], 0, 0, 0);
            __syncthreads();
        }

        int colg = colbase + wn * 64;
#pragma unroll
        for (int m = 0; m < 8; m++) {
#pragma unroll
            for (int j = 0; j < 4; j++) {
                int r = wm * 128 + m * 16 + kq * 4 + j;
                if (r < rows_e) {
                    size_t p = (size_t)off_e + rowbase + r;
                    int tok = token_list[p] >> 1;
#pragma unroll
                    for (int n = 0; n < 4; n++)
                        atomicAdd(&out[(size_t)tok * NE + colg + n * 16 + rr],
                                  acc[m][n][j]);
                }
            }
        }
    }
}

// ---------------------------------------------------------------------------
extern "C" void kernel_launch(void* const* d_in, const int* in_sizes, int n_in,
                              void* d_out, int out_size, void* d_ws, size_t ws_size,
                              hipStream_t stream)
{
    const float* x  = (const float*)d_in[0];
    const float* wr = (const float*)d_in[1];
    const float* w1 = (const float*)d_in[2];
    const float* w2 = (const float*)d_in[3];
    float* out = (float*)d_out;

    // workspace layout (~151.3 MB)
    char* ws = (char*)d_ws;
    size_t o = 0;
    __hip_bfloat16* h   = (__hip_bfloat16*)(ws + o); o += (size_t)P_TOT * DFFN * 2;  // 67.1MB
    __hip_bfloat16* xb  = (__hip_bfloat16*)(ws + o); o += (size_t)T_TOK * NE * 2;    // 16.8MB
    __hip_bfloat16* w1t = (__hip_bfloat16*)(ws + o); o += (size_t)NE * TW * 2;       // 33.6MB  [TW][NE]
    __hip_bfloat16* w2t = (__hip_bfloat16*)(ws + o); o += (size_t)TW * NE * 2;       // 33.6MB  [NE][TW]
    int*   sel_idx    = (int*)(ws + o);   o += P_TOT * 4;
    float* sel_wt     = (float*)(ws + o); o += P_TOT * 4;
    int*   token_list = (int*)(ws + o);   o += P_TOT * 4;
    int*   cnt        = (int*)(ws + o);   o += 64;
    int*   off        = (int*)(ws + o);   o += 64;
    int*   cursor     = (int*)(ws + o);   o += 64;
    int*   tile_tab   = (int*)(ws + o);   o += 128 * 4;
    int*   tile_n     = (int*)(ws + o);   o += 64;
    int*   wq         = (int*)(ws + o);   o += 64;
    float* z_part     = (float*)(ws + o); o += 32 * 4;
    float* p_part     = (float*)(ws + o); o += 32 * N_EXP * 4;

    hipMemsetAsync(d_out, 0, (size_t)out_size * sizeof(float), stream);

    cvt_x_kernel<<<T_TOK * NE / 4 / 256, 256, 0, stream>>>(x, (unsigned short*)xb);
    transpose_bf16_kernel<<<dim3(TW / 64, NE / 64), 256, 0, stream>>>(
        w1, (unsigned short*)w1t, NE, TW);     // w1 [NE][TW] -> w1t [TW][NE]
    transpose_bf16_kernel<<<dim3(NE / 64, TW / 64), 256, 0, stream>>>(
        w2, (unsigned short*)w2t, TW, NE);     // w2 [TW][NE] -> w2t [NE][TW]

    router_kernel<<<32, 256, 0, stream>>>(x, wr, sel_idx, sel_wt, z_part, p_part);
    finalize_router<<<1, 256, 0, stream>>>(sel_idx, z_part, p_part, cnt, off, cursor,
                                           tile_tab, tile_n, wq, out);
    scatter_kernel<<<64, 256, 0, stream>>>(sel_idx, off, cursor, token_list);

    // work-stealing grids: 512 blocks (<= 2 resident/CU), 256 threads
    gemm1_mfma<<<512, 256, 0, stream>>>(
        xb, w1t, token_list, sel_wt, cnt, off, tile_tab, tile_n, &wq[0], h);
    gemm2_mfma<<<512, 256, 0, stream>>>(
        h, w2t, token_list, cnt, off, tile_tab, tile_n, &wq[1], out);
}

// Round 5
// 571.215 us; speedup vs baseline: 1.3314x; 1.3314x over previous
//
#include <hip/hip_runtime.h>
#include <hip/hip_bf16.h>
#include <math.h>

#define T_TOK 8192
#define NE 1024
#define N_EXP 8
#define DFFN 2048
#define TW 16384        // total width = 8*2048
#define P_TOT 16384     // T_TOK * 2

#define BM 256
#define BN 256
#define BKT 32

typedef __attribute__((ext_vector_type(8))) short bf16x8;
typedef __attribute__((ext_vector_type(4))) float f32x4;

#define GLOAD_LDS16(g, l) __builtin_amdgcn_global_load_lds( \
    (const __attribute__((address_space(1))) void*)(g), \
    (__attribute__((address_space(3))) void*)(l), 16, 0, 0)

static __device__ __forceinline__ unsigned short f2bf(float f) {
    __hip_bfloat16 b = __float2bfloat16(f);
    return *(unsigned short*)&b;
}

// ---------------------------------------------------------------------------
// Kernel A: router — logits, softmax, top-2, normalized weights, loss partials
// (f32 throughout: bf16 logits would flip near-tie top-k selections)
// ---------------------------------------------------------------------------
__global__ __launch_bounds__(256) void router_kernel(
    const float* __restrict__ x, const float* __restrict__ wr,
    int* __restrict__ sel_idx, float* __restrict__ sel_wt,
    float* __restrict__ z_part, float* __restrict__ p_part)
{
    __shared__ float wrs[N_EXP * NE];   // 32 KB
    __shared__ float red[256];
    int tid = threadIdx.x;
    for (int i = tid; i < N_EXP * NE; i += 256) wrs[i] = wr[i];
    __syncthreads();

    int t = blockIdx.x * 256 + tid;   // T_TOK == 32*256 exactly
    float lg[N_EXP];
#pragma unroll
    for (int e = 0; e < N_EXP; e++) lg[e] = 0.f;

    const float4* x4 = (const float4*)(x + (size_t)t * NE);
    for (int n4 = 0; n4 < NE / 4; n4++) {
        float4 xv = x4[n4];
#pragma unroll
        for (int e = 0; e < N_EXP; e++) {
            const float* w = &wrs[e * NE + n4 * 4];
            lg[e] += xv.x * w[0] + xv.y * w[1] + xv.z * w[2] + xv.w * w[3];
        }
    }

    float m = lg[0];
#pragma unroll
    for (int e = 1; e < N_EXP; e++) m = fmaxf(m, lg[e]);
    float p[N_EXP], s = 0.f;
#pragma unroll
    for (int e = 0; e < N_EXP; e++) { p[e] = expf(lg[e] - m); s += p[e]; }
    float inv = 1.f / s;
#pragma unroll
    for (int e = 0; e < N_EXP; e++) p[e] *= inv;
    float lse = m + logf(s);

    int e0 = 0;
#pragma unroll
    for (int e = 1; e < N_EXP; e++) if (p[e] > p[e0]) e0 = e;
    int e1 = (e0 == 0) ? 1 : 0;
#pragma unroll
    for (int e = 0; e < N_EXP; e++) if (e != e0 && p[e] > p[e1]) e1 = e;

    float wn = 1.f / (p[e0] + p[e1]);
    sel_idx[t * 2 + 0] = e0;
    sel_idx[t * 2 + 1] = e1;
    sel_wt[t * 2 + 0] = p[e0] * wn;
    sel_wt[t * 2 + 1] = p[e1] * wn;

    red[tid] = lse * lse;
    __syncthreads();
    for (int st = 128; st > 0; st >>= 1) {
        if (tid < st) red[tid] += red[tid + st];
        __syncthreads();
    }
    if (tid == 0) z_part[blockIdx.x] = red[0];
#pragma unroll
    for (int e = 0; e < N_EXP; e++) {
        __syncthreads();
        red[tid] = p[e];
        __syncthreads();
        for (int st = 128; st > 0; st >>= 1) {
            if (tid < st) red[tid] += red[tid + st];
            __syncthreads();
        }
        if (tid == 0) p_part[blockIdx.x * N_EXP + e] = red[0];
    }
}

// ---------------------------------------------------------------------------
// Kernel B: counts (by scan), offsets, cursors, tile table, work-queue reset,
// aux-loss outputs
// ---------------------------------------------------------------------------
__global__ __launch_bounds__(256) void finalize_router(
    const int* __restrict__ sel_idx,
    const float* __restrict__ z_part, const float* __restrict__ p_part,
    int* __restrict__ cnt, int* __restrict__ off, int* __restrict__ cursor,
    int* __restrict__ tile_tab, int* __restrict__ tile_n,
    int* __restrict__ wq,
    float* __restrict__ out)
{
    __shared__ int redc[256];
    __shared__ int cnts[N_EXP];
    int tid = threadIdx.x;
    int c[N_EXP];
#pragma unroll
    for (int e = 0; e < N_EXP; e++) c[e] = 0;
    for (int i = tid; i < P_TOT; i += 256) c[sel_idx[i]]++;
#pragma unroll
    for (int e = 0; e < N_EXP; e++) {
        redc[tid] = c[e];
        __syncthreads();
        for (int st = 128; st > 0; st >>= 1) {
            if (tid < st) redc[tid] += redc[tid + st];
            __syncthreads();
        }
        if (tid == 0) cnts[e] = redc[0];
        __syncthreads();
    }
    if (tid == 0) {
        int o = 0;
        int nt = 0;
        for (int e = 0; e < N_EXP; e++) {
            cnt[e] = cnts[e];
            off[e] = o;
            o += cnts[e];
            cursor[e] = 0;
            for (int rb = 0; rb < cnts[e]; rb += BM)
                tile_tab[nt++] = (e << 20) | rb;
        }
        off[N_EXP] = o;
        tile_n[0] = nt;
        wq[0] = 0;       // gemm1 work-queue ticket
        wq[1] = 0;       // gemm2 work-queue ticket
        float zs = 0.f;
        for (int b = 0; b < 32; b++) zs += z_part[b];
        float lb = 0.f;
        float* tail = out + (size_t)T_TOK * NE;
        for (int e = 0; e < N_EXP; e++) {
            float ps = 0.f;
            for (int b = 0; b < 32; b++) ps += p_part[b * N_EXP + e];
            float fi = (float)cnts[e] / (float)P_TOT;
            float pi = ps / (float)T_TOK;
            lb += fi * pi;
            tail[2 + e] = fi;
        }
        tail[0] = zs / (float)T_TOK;       // router_z_loss
        tail[1] = 8.f * lb;                // load_balance_loss
    }
}

// ---------------------------------------------------------------------------
// Kernel C: scatter (token,slot) pairs into per-expert lists
// ---------------------------------------------------------------------------
__global__ __launch_bounds__(256) void scatter_kernel(
    const int* __restrict__ sel_idx, const int* __restrict__ off,
    int* __restrict__ cursor, int* __restrict__ token_list)
{
    int i = blockIdx.x * 256 + threadIdx.x;
    if (i < P_TOT) {
        int e = sel_idx[i];
        int pos = atomicAdd(&cursor[e], 1);
        token_list[off[e] + pos] = i;   // token = i>>1, slot = i&1
    }
}

// ---------------------------------------------------------------------------
// Kernel P1: x f32 -> bf16 (same layout)
// ---------------------------------------------------------------------------
__global__ __launch_bounds__(256) void cvt_x_kernel(
    const float* __restrict__ x, unsigned short* __restrict__ xb)
{
    int i = blockIdx.x * 256 + threadIdx.x;     // one float4 per thread
    float4 v = ((const float4*)x)[i];
    ushort4 o;
    o.x = f2bf(v.x); o.y = f2bf(v.y); o.z = f2bf(v.z); o.w = f2bf(v.w);
    ((ushort4*)xb)[i] = o;
}

// ---------------------------------------------------------------------------
// Kernel P2: transpose + convert: src [R][C] f32 -> dst [C][R] bf16
// vectorized: float4 loads, ushort4 stores
// ---------------------------------------------------------------------------
__global__ __launch_bounds__(256) void transpose_bf16_kernel(
    const float* __restrict__ src, unsigned short* __restrict__ dst,
    int R, int C)
{
    __shared__ float tile[64][65];
    int rb = blockIdx.y * 64, cb = blockIdx.x * 64;
    int tid = threadIdx.x;
#pragma unroll
    for (int p = 0; p < 4; p++) {
        int idx = p * 256 + tid;
        int r = idx >> 4, c4 = (idx & 15) << 2;
        float4 v = *(const float4*)&src[(size_t)(rb + r) * C + cb + c4];
        tile[r][c4 + 0] = v.x; tile[r][c4 + 1] = v.y;
        tile[r][c4 + 2] = v.z; tile[r][c4 + 3] = v.w;
    }
    __syncthreads();
#pragma unroll
    for (int p = 0; p < 4; p++) {
        int idx = p * 256 + tid;
        int c = idx >> 4, r4 = (idx & 15) << 2;
        ushort4 o;
        o.x = f2bf(tile[r4 + 0][c]); o.y = f2bf(tile[r4 + 1][c]);
        o.z = f2bf(tile[r4 + 2][c]); o.w = f2bf(tile[r4 + 3][c]);
        *(ushort4*)&dst[(size_t)(cb + c) * R + rb + r4] = o;
    }
}

// ---------------------------------------------------------------------------
// Kernel D: grouped GEMM1. 256x256 tile, BK=32, 8 waves (2x4), per-wave
// 128x64 (acc[8][4]). One block per CU (64KB LDS dbuf), persistent
// work-queue over (row-tile, col-tile). XOR-swizzled LDS (source-side
// pre-swizzle + matching read XOR) -> conflict-free ds_read_b128.
// h[p,:] = selw[p] * gelu(xb[tok(p),:] @ W1_e)
// ---------------------------------------------------------------------------
__global__ __launch_bounds__(512) void gemm1_mfma(
    const __hip_bfloat16* __restrict__ xb, const __hip_bfloat16* __restrict__ w1t,
    const int* __restrict__ token_list, const float* __restrict__ sel_wt,
    const int* __restrict__ cnt, const int* __restrict__ off,
    const int* __restrict__ tile_tab, const int* __restrict__ tile_n,
    int* __restrict__ wq,
    __hip_bfloat16* __restrict__ h)
{
    __shared__ __align__(16) __hip_bfloat16 As[2][BM * BKT];  // 2 x 16 KB
    __shared__ __align__(16) __hip_bfloat16 Bs[2][BN * BKT];  // 2 x 16 KB
    volatile int* wkslot = (volatile int*)&As[0][0];

    int tid = threadIdx.x;
    int wid = tid >> 6, lane = tid & 63;
    int wm = wid >> 2, wn = wid & 3;            // 2 x 4 wave grid
    int rr = lane & 15, kq = lane >> 4;
    int kqa = kq ^ ((rr >> 1) & 3);             // read-side swizzle
    int ksw = (lane & 3) ^ ((lane >> 3) & 3);   // source-side swizzle
    int nwork = tile_n[0] * 8;                  // 8 col-tiles of 256

    for (;;) {
        if (tid == 0) *wkslot = atomicAdd(wq, 1);
        __syncthreads();
        int wk = *wkslot;
        __syncthreads();
        if (wk >= nwork) return;

        int tab = tile_tab[wk >> 3];
        int e = tab >> 20, rowbase = tab & 0xFFFFF;
        int off_e = off[e];
        int rows_e = cnt[e] - rowbase;
        int colbase = (wk & 7) * BN;

        // staging sources: wave wid stages chunks 2wid,2wid+1 (A and B)
        const __hip_bfloat16* asrc[2];
        const __hip_bfloat16* bsrc[2];
#pragma unroll
        for (int j = 0; j < 2; j++) {
            int r = wid * 32 + j * 16 + (lane >> 2);
            int ent = token_list[off_e + rowbase + ((r < rows_e) ? r : 0)];
            asrc[j] = xb + (size_t)(ent >> 1) * NE + ksw * 8;
            int cc = colbase + wid * 32 + j * 16 + (lane >> 2);
            bsrc[j] = w1t + (size_t)(e * DFFN + cc) * NE + ksw * 8;
        }

        f32x4 acc[8][4] = {};

#pragma unroll
        for (int j = 0; j < 2; j++) {
            GLOAD_LDS16(asrc[j], &As[0][(wid * 2 + j) * 512]);
            GLOAD_LDS16(bsrc[j], &Bs[0][(wid * 2 + j) * 512]);
        }
        __syncthreads();

        for (int t = 0; t < NE / BKT; t++) {
            int cur = t & 1;
            if (t + 1 < NE / BKT) {
                int kb = (t + 1) * BKT;
#pragma unroll
                for (int j = 0; j < 2; j++) {
                    GLOAD_LDS16(asrc[j] + kb, &As[cur ^ 1][(wid * 2 + j) * 512]);
                    GLOAD_LDS16(bsrc[j] + kb, &Bs[cur ^ 1][(wid * 2 + j) * 512]);
                }
            }
            bf16x8 af[8], bfr[4];
#pragma unroll
            for (int m = 0; m < 8; m++)
                af[m] = *(const bf16x8*)&As[cur][(wm * 128 + m * 16 + rr) * BKT + kqa * 8];
#pragma unroll
            for (int n = 0; n < 4; n++)
                bfr[n] = *(const bf16x8*)&Bs[cur][(wn * 64 + n * 16 + rr) * BKT + kqa * 8];
#pragma unroll
            for (int m = 0; m < 8; m++)
#pragma unroll
                for (int n = 0; n < 4; n++)
                    acc[m][n] = __builtin_amdgcn_mfma_f32_16x16x32_bf16(
                        af[m], bfr[n], acc[m][n], 0, 0, 0);
            __syncthreads();
        }

        int colg = colbase + wn * 64;
#pragma unroll
        for (int m = 0; m < 8; m++) {
#pragma unroll
            for (int j = 0; j < 4; j++) {
                int r = wm * 128 + m * 16 + kq * 4 + j;
                if (r < rows_e) {
                    size_t p = (size_t)off_e + rowbase + r;
                    float wgt = sel_wt[token_list[p]];
#pragma unroll
                    for (int n = 0; n < 4; n++) {
                        float v = acc[m][n][j];
                        float g = 0.5f * v * (1.f + erff(v * 0.70710678118f));
                        h[p * DFFN + colg + n * 16 + rr] = __float2bfloat16(wgt * g);
                    }
                }
            }
        }
    }
}

// ---------------------------------------------------------------------------
// Kernel E: grouped GEMM2, same structure, split-K=2, atomic f32 out.
// out[tok(p),:] += h[p,:] @ W2_e
// ---------------------------------------------------------------------------
__global__ __launch_bounds__(512) void gemm2_mfma(
    const __hip_bfloat16* __restrict__ h, const __hip_bfloat16* __restrict__ w2t,
    const int* __restrict__ token_list,
    const int* __restrict__ cnt, const int* __restrict__ off,
    const int* __restrict__ tile_tab, const int* __restrict__ tile_n,
    int* __restrict__ wq,
    float* __restrict__ out)
{
    __shared__ __align__(16) __hip_bfloat16 As[2][BM * BKT];
    __shared__ __align__(16) __hip_bfloat16 Bs[2][BN * BKT];
    volatile int* wkslot = (volatile int*)&As[0][0];

    int tid = threadIdx.x;
    int wid = tid >> 6, lane = tid & 63;
    int wm = wid >> 2, wn = wid & 3;
    int rr = lane & 15, kq = lane >> 4;
    int kqa = kq ^ ((rr >> 1) & 3);
    int ksw = (lane & 3) ^ ((lane >> 3) & 3);
    int nwork = tile_n[0] * 8;                  // 4 col-tiles x 2 splitK

    for (;;) {
        if (tid == 0) *wkslot = atomicAdd(wq, 1);
        __syncthreads();
        int wk = *wkslot;
        __syncthreads();
        if (wk >= nwork) return;

        int tab = tile_tab[wk >> 3];
        int e = tab >> 20, rowbase = tab & 0xFFFFF;
        int off_e = off[e];
        int rows_e = cnt[e] - rowbase;
        int colbase = ((wk >> 1) & 3) * BN;
        int k0 = (wk & 1) * (DFFN / 2);         // split-K offset

        const __hip_bfloat16* asrc[2];
        const __hip_bfloat16* bsrc[2];
#pragma unroll
        for (int j = 0; j < 2; j++) {
            int r = wid * 32 + j * 16 + (lane >> 2);
            int pr = off_e + rowbase + ((r < rows_e) ? r : 0);
            asrc[j] = h + (size_t)pr * DFFN + k0 + ksw * 8;
            int cc = colbase + wid * 32 + j * 16 + (lane >> 2);
            bsrc[j] = w2t + (size_t)cc * TW + e * DFFN + k0 + ksw * 8;
        }

        f32x4 acc[8][4] = {};

#pragma unroll
        for (int j = 0; j < 2; j++) {
            GLOAD_LDS16(asrc[j], &As[0][(wid * 2 + j) * 512]);
            GLOAD_LDS16(bsrc[j], &Bs[0][(wid * 2 + j) * 512]);
        }
        __syncthreads();

        const int NKT = (DFFN / 2) / BKT;   // 32
        for (int t = 0; t < NKT; t++) {
            int cur = t & 1;
            if (t + 1 < NKT) {
                int kb = (t + 1) * BKT;
#pragma unroll
                for (int j = 0; j < 2; j++) {
                    GLOAD_LDS16(asrc[j] + kb, &As[cur ^ 1][(wid * 2 + j) * 512]);
                    GLOAD_LDS16(bsrc[j] + kb, &Bs[cur ^ 1][(wid * 2 + j) * 512]);
                }
            }
            bf16x8 af[8], bfr[4];
#pragma unroll
            for (int m = 0; m < 8; m++)
                af[m] = *(const bf16x8*)&As[cur][(wm * 128 + m * 16 + rr) * BKT + kqa * 8];
#pragma unroll
            for (int n = 0; n < 4; n++)
                bfr[n] = *(const bf16x8*)&Bs[cur][(wn * 64 + n * 16 + rr) * BKT + kqa * 8];
#pragma unroll
            for (int m = 0; m < 8; m++)
#pragma unroll
                for (int n = 0; n < 4; n++)
                    acc[m][n] = __builtin_amdgcn_mfma_f32_16x16x32_bf16(
                        af[m], bfr[n], acc[m][n], 0, 0, 0);
            __syncthreads();
        }

        int colg = colbase + wn * 64;
#pragma unroll
        for (int m = 0; m < 8; m++) {
#pragma unroll
            for (int j = 0; j < 4; j++) {
                int r = wm * 128 + m * 16 + kq * 4 + j;
                if (r < rows_e) {
                    size_t p = (size_t)off_e + rowbase + r;
                    int tok = token_list[p] >> 1;
#pragma unroll
                    for (int n = 0; n < 4; n++)
                        atomicAdd(&out[(size_t)tok * NE + colg + n * 16 + rr],
                                  acc[m][n][j]);
                }
            }
        }
    }
}

// ---------------------------------------------------------------------------
extern "C" void kernel_launch(void* const* d_in, const int* in_sizes, int n_in,
                              void* d_out, int out_size, void* d_ws, size_t ws_size,
                              hipStream_t stream)
{
    const float* x  = (const float*)d_in[0];
    const float* wr = (const float*)d_in[1];
    const float* w1 = (const float*)d_in[2];
    const float* w2 = (const float*)d_in[3];
    float* out = (float*)d_out;

    // workspace layout (~151.3 MB)
    char* ws = (char*)d_ws;
    size_t o = 0;
    __hip_bfloat16* h   = (__hip_bfloat16*)(ws + o); o += (size_t)P_TOT * DFFN * 2;  // 67.1MB
    __hip_bfloat16* xb  = (__hip_bfloat16*)(ws + o); o += (size_t)T_TOK * NE * 2;    // 16.8MB
    __hip_bfloat16* w1t = (__hip_bfloat16*)(ws + o); o += (size_t)NE * TW * 2;       // 33.6MB  [TW][NE]
    __hip_bfloat16* w2t = (__hip_bfloat16*)(ws + o); o += (size_t)TW * NE * 2;       // 33.6MB  [NE][TW]
    int*   sel_idx    = (int*)(ws + o);   o += P_TOT * 4;
    float* sel_wt     = (float*)(ws + o); o += P_TOT * 4;
    int*   token_list = (int*)(ws + o);   o += P_TOT * 4;
    int*   cnt        = (int*)(ws + o);   o += 64;
    int*   off        = (int*)(ws + o);   o += 64;
    int*   cursor     = (int*)(ws + o);   o += 64;
    int*   tile_tab   = (int*)(ws + o);   o += 128 * 4;
    int*   tile_n     = (int*)(ws + o);   o += 64;
    int*   wq         = (int*)(ws + o);   o += 64;
    float* z_part     = (float*)(ws + o); o += 32 * 4;
    float* p_part     = (float*)(ws + o); o += 32 * N_EXP * 4;

    hipMemsetAsync(d_out, 0, (size_t)out_size * sizeof(float), stream);

    cvt_x_kernel<<<T_TOK * NE / 4 / 256, 256, 0, stream>>>(x, (unsigned short*)xb);
    transpose_bf16_kernel<<<dim3(TW / 64, NE / 64), 256, 0, stream>>>(
        w1, (unsigned short*)w1t, NE, TW);     // w1 [NE][TW] -> w1t [TW][NE]
    transpose_bf16_kernel<<<dim3(NE / 64, TW / 64), 256, 0, stream>>>(
        w2, (unsigned short*)w2t, TW, NE);     // w2 [TW][NE] -> w2t [NE][TW]

    router_kernel<<<32, 256, 0, stream>>>(x, wr, sel_idx, sel_wt, z_part, p_part);
    finalize_router<<<1, 256, 0, stream>>>(sel_idx, z_part, p_part, cnt, off, cursor,
                                           tile_tab, tile_n, wq, out);
    scatter_kernel<<<64, 256, 0, stream>>>(sel_idx, off, cursor, token_list);

    // persistent blocks, 1 block/CU (64KB LDS), work-queue over tiles
    gemm1_mfma<<<512, 512, 0, stream>>>(
        xb, w1t, token_list, sel_wt, cnt, off, tile_tab, tile_n, &wq[0], h);
    gemm2_mfma<<<512, 512, 0, stream>>>(
        h, w2t, token_list, cnt, off, tile_tab, tile_n, &wq[1], out);
}

// Round 6
// 505.811 us; speedup vs baseline: 1.5036x; 1.1293x over previous
//
#include <hip/hip_runtime.h>
#include <hip/hip_bf16.h>
#include <math.h>

#define T_TOK 8192
#define NE 1024
#define N_EXP 8
#define DFFN 2048
#define TW 16384        // total width = 8*2048
#define P_TOT 16384     // T_TOK * 2

#define BMT 128         // GEMM row-tile
#define BNT 128         // GEMM col-tile
#define BKT 64          // GEMM K-tile

typedef __attribute__((ext_vector_type(8))) short bf16x8;
typedef __attribute__((ext_vector_type(4))) float f32x4;

#define GLOAD_LDS16(g, l) __builtin_amdgcn_global_load_lds( \
    (const __attribute__((address_space(1))) void*)(g), \
    (__attribute__((address_space(3))) void*)(l), 16, 0, 0)

static __device__ __forceinline__ unsigned short f2bf(float f) {
    __hip_bfloat16 b = __float2bfloat16(f);
    return *(unsigned short*)&b;
}

// ---------------------------------------------------------------------------
// Kernel A: router — logits, softmax, top-2, normalized weights, loss partials
// (f32 throughout: bf16 logits would flip near-tie top-k selections)
// ---------------------------------------------------------------------------
__global__ __launch_bounds__(256) void router_kernel(
    const float* __restrict__ x, const float* __restrict__ wr,
    int* __restrict__ sel_idx, float* __restrict__ sel_wt,
    float* __restrict__ z_part, float* __restrict__ p_part)
{
    __shared__ float wrs[N_EXP * NE];   // 32 KB
    __shared__ float red[256];
    int tid = threadIdx.x;
    for (int i = tid; i < N_EXP * NE; i += 256) wrs[i] = wr[i];
    __syncthreads();

    int t = blockIdx.x * 256 + tid;   // T_TOK == 32*256 exactly
    float lg[N_EXP];
#pragma unroll
    for (int e = 0; e < N_EXP; e++) lg[e] = 0.f;

    const float4* x4 = (const float4*)(x + (size_t)t * NE);
    for (int n4 = 0; n4 < NE / 4; n4++) {
        float4 xv = x4[n4];
#pragma unroll
        for (int e = 0; e < N_EXP; e++) {
            const float* w = &wrs[e * NE + n4 * 4];
            lg[e] += xv.x * w[0] + xv.y * w[1] + xv.z * w[2] + xv.w * w[3];
        }
    }

    float m = lg[0];
#pragma unroll
    for (int e = 1; e < N_EXP; e++) m = fmaxf(m, lg[e]);
    float p[N_EXP], s = 0.f;
#pragma unroll
    for (int e = 0; e < N_EXP; e++) { p[e] = expf(lg[e] - m); s += p[e]; }
    float inv = 1.f / s;
#pragma unroll
    for (int e = 0; e < N_EXP; e++) p[e] *= inv;
    float lse = m + logf(s);

    int e0 = 0;
#pragma unroll
    for (int e = 1; e < N_EXP; e++) if (p[e] > p[e0]) e0 = e;
    int e1 = (e0 == 0) ? 1 : 0;
#pragma unroll
    for (int e = 0; e < N_EXP; e++) if (e != e0 && p[e] > p[e1]) e1 = e;

    float wn = 1.f / (p[e0] + p[e1]);
    sel_idx[t * 2 + 0] = e0;
    sel_idx[t * 2 + 1] = e1;
    sel_wt[t * 2 + 0] = p[e0] * wn;
    sel_wt[t * 2 + 1] = p[e1] * wn;

    red[tid] = lse * lse;
    __syncthreads();
    for (int st = 128; st > 0; st >>= 1) {
        if (tid < st) red[tid] += red[tid + st];
        __syncthreads();
    }
    if (tid == 0) z_part[blockIdx.x] = red[0];
#pragma unroll
    for (int e = 0; e < N_EXP; e++) {
        __syncthreads();
        red[tid] = p[e];
        __syncthreads();
        for (int st = 128; st > 0; st >>= 1) {
            if (tid < st) red[tid] += red[tid + st];
            __syncthreads();
        }
        if (tid == 0) p_part[blockIdx.x * N_EXP + e] = red[0];
    }
}

// ---------------------------------------------------------------------------
// Kernel B: counts (by scan), offsets, cursors, tile table, aux-loss outputs
// ---------------------------------------------------------------------------
__global__ __launch_bounds__(256) void finalize_router(
    const int* __restrict__ sel_idx,
    const float* __restrict__ z_part, const float* __restrict__ p_part,
    int* __restrict__ cnt, int* __restrict__ off, int* __restrict__ cursor,
    int* __restrict__ tile_tab, int* __restrict__ tile_n,
    float* __restrict__ out)
{
    __shared__ int redc[256];
    __shared__ int cnts[N_EXP];
    int tid = threadIdx.x;
    int c[N_EXP];
#pragma unroll
    for (int e = 0; e < N_EXP; e++) c[e] = 0;
    for (int i = tid; i < P_TOT; i += 256) c[sel_idx[i]]++;
#pragma unroll
    for (int e = 0; e < N_EXP; e++) {
        redc[tid] = c[e];
        __syncthreads();
        for (int st = 128; st > 0; st >>= 1) {
            if (tid < st) redc[tid] += redc[tid + st];
            __syncthreads();
        }
        if (tid == 0) cnts[e] = redc[0];
        __syncthreads();
    }
    if (tid == 0) {
        int o = 0;
        int nt = 0;
        for (int e = 0; e < N_EXP; e++) {
            cnt[e] = cnts[e];
            off[e] = o;
            o += cnts[e];
            cursor[e] = 0;
            for (int rb = 0; rb < cnts[e]; rb += BMT)
                tile_tab[nt++] = (e << 20) | rb;
        }
        off[N_EXP] = o;
        tile_n[0] = nt;
        float zs = 0.f;
        for (int b = 0; b < 32; b++) zs += z_part[b];
        float lb = 0.f;
        float* tail = out + (size_t)T_TOK * NE;
        for (int e = 0; e < N_EXP; e++) {
            float ps = 0.f;
            for (int b = 0; b < 32; b++) ps += p_part[b * N_EXP + e];
            float fi = (float)cnts[e] / (float)P_TOT;
            float pi = ps / (float)T_TOK;
            lb += fi * pi;
            tail[2 + e] = fi;
        }
        tail[0] = zs / (float)T_TOK;       // router_z_loss
        tail[1] = 8.f * lb;                // load_balance_loss
    }
}

// ---------------------------------------------------------------------------
// Kernel C: scatter (token,slot) pairs into per-expert lists
// ---------------------------------------------------------------------------
__global__ __launch_bounds__(256) void scatter_kernel(
    const int* __restrict__ sel_idx, const int* __restrict__ off,
    int* __restrict__ cursor, int* __restrict__ token_list)
{
    int i = blockIdx.x * 256 + threadIdx.x;
    if (i < P_TOT) {
        int e = sel_idx[i];
        int pos = atomicAdd(&cursor[e], 1);
        token_list[off[e] + pos] = i;   // token = i>>1, slot = i&1
    }
}

// ---------------------------------------------------------------------------
// Kernel G: gather + convert: xg[p,:] = bf16(x[tok(p),:]) (expert-sorted A)
// ---------------------------------------------------------------------------
__global__ __launch_bounds__(256) void gather_x_kernel(
    const float* __restrict__ x, const int* __restrict__ token_list,
    unsigned short* __restrict__ xg)
{
    int idx = blockIdx.x * 256 + threadIdx.x;     // P_TOT*128 threads, 8 elems each
    int p = idx >> 7, c8 = (idx & 127) << 3;
    int tok = token_list[p] >> 1;
    const float4* s = (const float4*)(x + (size_t)tok * NE + c8);
    float4 v0 = s[0], v1 = s[1];
    ushort4 o0, o1;
    o0.x = f2bf(v0.x); o0.y = f2bf(v0.y); o0.z = f2bf(v0.z); o0.w = f2bf(v0.w);
    o1.x = f2bf(v1.x); o1.y = f2bf(v1.y); o1.z = f2bf(v1.z); o1.w = f2bf(v1.w);
    *(ushort4*)&xg[(size_t)p * NE + c8] = o0;
    *(ushort4*)&xg[(size_t)p * NE + c8 + 4] = o1;
}

// ---------------------------------------------------------------------------
// Kernel P2: transpose + convert: src [R][C] f32 -> dst [C][R] bf16
// ---------------------------------------------------------------------------
__global__ __launch_bounds__(256) void transpose_bf16_kernel(
    const float* __restrict__ src, unsigned short* __restrict__ dst,
    int R, int C)
{
    __shared__ float tile[64][65];
    int rb = blockIdx.y * 64, cb = blockIdx.x * 64;
    int tid = threadIdx.x;
#pragma unroll
    for (int p = 0; p < 4; p++) {
        int idx = p * 256 + tid;
        int r = idx >> 4, c4 = (idx & 15) << 2;
        float4 v = *(const float4*)&src[(size_t)(rb + r) * C + cb + c4];
        tile[r][c4 + 0] = v.x; tile[r][c4 + 1] = v.y;
        tile[r][c4 + 2] = v.z; tile[r][c4 + 3] = v.w;
    }
    __syncthreads();
#pragma unroll
    for (int p = 0; p < 4; p++) {
        int idx = p * 256 + tid;
        int c = idx >> 4, r4 = (idx & 15) << 2;
        ushort4 o;
        o.x = f2bf(tile[r4 + 0][c]); o.y = f2bf(tile[r4 + 1][c]);
        o.z = f2bf(tile[r4 + 2][c]); o.w = f2bf(tile[r4 + 3][c]);
        *(ushort4*)&dst[(size_t)(cb + c) * R + rb + r4] = o;
    }
}

// ---------------------------------------------------------------------------
// Grouped GEMM core: 128x128 tile, BK=64, 4 waves (2x2), per-wave 64x64.
// Double-buffered 64KB LDS (2 blocks/CU). Counted vmcnt across RAW barriers:
//   STAGE(next) -> sched_barrier -> s_waitcnt vmcnt(8) -> s_barrier ->
//   ds_read(+XOR slot swizzle) + MFMA -> s_barrier
// Loads for tile t+1 stay in flight through the whole compute of tile t.
// 8-slot XOR swizzle: source chunk ksw=(lane&7)^((lane>>3)&7); read slot
// (kh*4+kq)^(rr&7). Octet-of-lanes covers all 32 banks -> conflict-free.
// ---------------------------------------------------------------------------
#define STAGE(buf, kb) do {                                              \
    _Pragma("unroll")                                                    \
    for (int j = 0; j < 4; j++) {                                        \
        GLOAD_LDS16(ga[j] + (kb), &As[buf][(wid * 4 + j) * 512]);        \
        GLOAD_LDS16(gb[j] + (kb), &Bs[buf][(wid * 4 + j) * 512]);        \
    } } while (0)

#define GEMM_MAIN_LOOP(NKT)                                              \
    STAGE(0, 0);                                                         \
    for (int t = 0; t < (NKT); t++) {                                    \
        int cur = t & 1;                                                 \
        if (t + 1 < (NKT)) {                                             \
            STAGE(cur ^ 1, (t + 1) * BKT);                               \
            __builtin_amdgcn_sched_barrier(0);                           \
            asm volatile("s_waitcnt vmcnt(8)" ::: "memory");             \
        } else {                                                         \
            asm volatile("s_waitcnt vmcnt(0)" ::: "memory");             \
        }                                                                \
        __builtin_amdgcn_s_barrier();                                    \
        __builtin_amdgcn_sched_barrier(0);                               \
        _Pragma("unroll")                                                \
        for (int kh = 0; kh < 2; kh++) {                                 \
            bf16x8 af[4], bfr[4];                                        \
            _Pragma("unroll")                                            \
            for (int m = 0; m < 4; m++)                                  \
                af[m] = *(const bf16x8*)&As[cur][(wm * 64 + m * 16 + rr) * 64 \
                        + ((kh * 4 + kq) ^ (rr & 7)) * 8];               \
            _Pragma("unroll")                                            \
            for (int n = 0; n < 4; n++)                                  \
                bfr[n] = *(const bf16x8*)&Bs[cur][(wn * 64 + n * 16 + rr) * 64 \
                        + ((kh * 4 + kq) ^ (rr & 7)) * 8];               \
            __builtin_amdgcn_s_setprio(1);                               \
            _Pragma("unroll")                                            \
            for (int m = 0; m < 4; m++)                                  \
                _Pragma("unroll")                                        \
                for (int n = 0; n < 4; n++)                              \
                    acc[m][n] = __builtin_amdgcn_mfma_f32_16x16x32_bf16( \
                        af[m], bfr[n], acc[m][n], 0, 0, 0);              \
            __builtin_amdgcn_s_setprio(0);                               \
        }                                                                \
        asm volatile("" ::: "memory");                                   \
        __builtin_amdgcn_sched_barrier(0);                               \
        __builtin_amdgcn_s_barrier();                                    \
    }

// ---------------------------------------------------------------------------
// Kernel D: grouped GEMM1:  h[p,:] = selw[p] * gelu(xg[p,:] @ W1_e)
// ---------------------------------------------------------------------------
__global__ __launch_bounds__(256) void gemm1_mfma(
    const __hip_bfloat16* __restrict__ xg, const __hip_bfloat16* __restrict__ w1t,
    const int* __restrict__ token_list, const float* __restrict__ sel_wt,
    const int* __restrict__ cnt, const int* __restrict__ off,
    const int* __restrict__ tile_tab, const int* __restrict__ tile_n,
    __hip_bfloat16* __restrict__ h)
{
    int flat = blockIdx.x;
    if (flat >= tile_n[0]) return;
    int tab = tile_tab[flat];
    int e = tab >> 20, rowbase = tab & 0xFFFFF;
    int off_e = off[e];
    int rows_e = cnt[e] - rowbase;
    int colbase = blockIdx.y * BNT;

    __shared__ __align__(16) __hip_bfloat16 As[2][BMT * BKT];  // 2 x 16 KB
    __shared__ __align__(16) __hip_bfloat16 Bs[2][BNT * BKT];  // 2 x 16 KB

    int tid = threadIdx.x;
    int wid = tid >> 6, lane = tid & 63;
    int wm = wid >> 1, wn = wid & 1;
    int rr = lane & 15, kq = lane >> 4;
    int ksw = (lane & 7) ^ ((lane >> 3) & 7);   // source-side 16B-chunk swizzle

    const __hip_bfloat16* ga[4];
    const __hip_bfloat16* gb[4];
#pragma unroll
    for (int j = 0; j < 4; j++) {
        int r = (wid * 4 + j) * 8 + (lane >> 3);             // 0..127
        int ar = (r < rows_e) ? r : 0;
        ga[j] = xg + ((size_t)off_e + rowbase + ar) * NE + ksw * 8;
        int cc = colbase + (wid * 4 + j) * 8 + (lane >> 3);
        gb[j] = w1t + (size_t)(e * DFFN + cc) * NE + ksw * 8;
    }

    f32x4 acc[4][4] = {};
    GEMM_MAIN_LOOP(NE / BKT)

    int colg = colbase + wn * 64;
#pragma unroll
    for (int m = 0; m < 4; m++) {
#pragma unroll
        for (int j = 0; j < 4; j++) {
            int r = wm * 64 + m * 16 + kq * 4 + j;
            if (r < rows_e) {
                size_t p = (size_t)off_e + rowbase + r;
                float wgt = sel_wt[token_list[p]];
#pragma unroll
                for (int n = 0; n < 4; n++) {
                    float v = acc[m][n][j];
                    float g = 0.5f * v * (1.f + erff(v * 0.70710678118f));
                    h[p * DFFN + colg + n * 16 + rr] = __float2bfloat16(wgt * g);
                }
            }
        }
    }
}

// ---------------------------------------------------------------------------
// Kernel E: grouped GEMM2:  out[tok(p),:] += h[p,:] @ W2_e   (atomic f32)
// ---------------------------------------------------------------------------
__global__ __launch_bounds__(256) void gemm2_mfma(
    const __hip_bfloat16* __restrict__ h, const __hip_bfloat16* __restrict__ w2t,
    const int* __restrict__ token_list,
    const int* __restrict__ cnt, const int* __restrict__ off,
    const int* __restrict__ tile_tab, const int* __restrict__ tile_n,
    float* __restrict__ out)
{
    int flat = blockIdx.x;
    if (flat >= tile_n[0]) return;
    int tab = tile_tab[flat];
    int e = tab >> 20, rowbase = tab & 0xFFFFF;
    int off_e = off[e];
    int rows_e = cnt[e] - rowbase;
    int colbase = blockIdx.y * BNT;

    __shared__ __align__(16) __hip_bfloat16 As[2][BMT * BKT];
    __shared__ __align__(16) __hip_bfloat16 Bs[2][BNT * BKT];

    int tid = threadIdx.x;
    int wid = tid >> 6, lane = tid & 63;
    int wm = wid >> 1, wn = wid & 1;
    int rr = lane & 15, kq = lane >> 4;
    int ksw = (lane & 7) ^ ((lane >> 3) & 7);

    const __hip_bfloat16* ga[4];
    const __hip_bfloat16* gb[4];
#pragma unroll
    for (int j = 0; j < 4; j++) {
        int r = (wid * 4 + j) * 8 + (lane >> 3);
        int ar = (r < rows_e) ? r : 0;
        ga[j] = h + ((size_t)off_e + rowbase + ar) * DFFN + ksw * 8;
        int cc = colbase + (wid * 4 + j) * 8 + (lane >> 3);
        gb[j] = w2t + (size_t)cc * TW + e * DFFN + ksw * 8;
    }

    f32x4 acc[4][4] = {};
    GEMM_MAIN_LOOP(DFFN / BKT)

    int colg = colbase + wn * 64;
#pragma unroll
    for (int m = 0; m < 4; m++) {
#pragma unroll
        for (int j = 0; j < 4; j++) {
            int r = wm * 64 + m * 16 + kq * 4 + j;
            if (r < rows_e) {
                size_t p = (size_t)off_e + rowbase + r;
                int tok = token_list[p] >> 1;
#pragma unroll
                for (int n = 0; n < 4; n++)
                    atomicAdd(&out[(size_t)tok * NE + colg + n * 16 + rr],
                              acc[m][n][j]);
            }
        }
    }
}

// ---------------------------------------------------------------------------
extern "C" void kernel_launch(void* const* d_in, const int* in_sizes, int n_in,
                              void* d_out, int out_size, void* d_ws, size_t ws_size,
                              hipStream_t stream)
{
    const float* x  = (const float*)d_in[0];
    const float* wr = (const float*)d_in[1];
    const float* w1 = (const float*)d_in[2];
    const float* w2 = (const float*)d_in[3];
    float* out = (float*)d_out;

    // workspace layout (~151.3 MB)
    char* ws = (char*)d_ws;
    size_t o = 0;
    __hip_bfloat16* h   = (__hip_bfloat16*)(ws + o); o += (size_t)P_TOT * DFFN * 2;  // 67.1MB
    __hip_bfloat16* xg  = (__hip_bfloat16*)(ws + o); o += (size_t)P_TOT * NE * 2;    // 33.6MB
    __hip_bfloat16* w1t = (__hip_bfloat16*)(ws + o); o += (size_t)NE * TW * 2;       // 33.6MB  [TW][NE]
    __hip_bfloat16* w2t = (__hip_bfloat16*)(ws + o); o += (size_t)TW * NE * 2;       // 33.6MB  [NE][TW]
    int*   sel_idx    = (int*)(ws + o);   o += P_TOT * 4;
    float* sel_wt     = (float*)(ws + o); o += P_TOT * 4;
    int*   token_list = (int*)(ws + o);   o += P_TOT * 4;
    int*   cnt        = (int*)(ws + o);   o += 64;
    int*   off        = (int*)(ws + o);   o += 64;
    int*   cursor     = (int*)(ws + o);   o += 64;
    int*   tile_tab   = (int*)(ws + o);   o += 256 * 4;
    int*   tile_n     = (int*)(ws + o);   o += 64;
    float* z_part     = (float*)(ws + o); o += 32 * 4;
    float* p_part     = (float*)(ws + o); o += 32 * N_EXP * 4;

    hipMemsetAsync(d_out, 0, (size_t)out_size * sizeof(float), stream);

    router_kernel<<<32, 256, 0, stream>>>(x, wr, sel_idx, sel_wt, z_part, p_part);
    finalize_router<<<1, 256, 0, stream>>>(sel_idx, z_part, p_part, cnt, off, cursor,
                                           tile_tab, tile_n, out);
    scatter_kernel<<<64, 256, 0, stream>>>(sel_idx, off, cursor, token_list);
    gather_x_kernel<<<P_TOT * (NE / 8) / 256, 256, 0, stream>>>(x, token_list,
                                                                (unsigned short*)xg);
    transpose_bf16_kernel<<<dim3(TW / 64, NE / 64), 256, 0, stream>>>(
        w1, (unsigned short*)w1t, NE, TW);     // w1 [NE][TW] -> w1t [TW][NE]
    transpose_bf16_kernel<<<dim3(NE / 64, TW / 64), 256, 0, stream>>>(
        w2, (unsigned short*)w2t, TW, NE);     // w2 [TW][NE] -> w2t [NE][TW]

    // max row-tiles: sum_e ceil(cnt_e/128) <= 128 + 7 = 135 -> grid.x = 136
    gemm1_mfma<<<dim3(136, DFFN / BNT), 256, 0, stream>>>(
        xg, w1t, token_list, sel_wt, cnt, off, tile_tab, tile_n, h);
    gemm2_mfma<<<dim3(136, NE / BNT), 256, 0, stream>>>(
        h, w2t, token_list, cnt, off, tile_tab, tile_n, out);
}